// Round 15
// baseline (185.963 us; speedup 1.0000x reference)
//
#include <hip/hip_runtime.h>
#include <hip/hip_bf16.h>
#include <math.h>

#define NPTS 2048
#define NBATCH 8
#define MTOT (NBATCH*NPTS)
#define KROW 4096   // conv K: 128 rows * 32 cols
#define OUTC 64

using bf16x8 = __attribute__((ext_vector_type(8))) short;
using f32x4  = __attribute__((ext_vector_type(4))) float;
using f32x2  = __attribute__((ext_vector_type(2))) float;

__device__ __forceinline__ unsigned short f2bf(float f) {
    unsigned u = __float_as_uint(f);
    unsigned r = u + 0x7FFFu + ((u >> 16) & 1u);
    return (unsigned short)(r >> 16);
}
// pair-pack via compiler-fused v_cvt_pk_bf16_f32 (RNE, identical to f2bf)
__device__ __forceinline__ unsigned pk2bf(float lo, float hi) {
    __hip_bfloat162 h2 = __float22bfloat162_rn(make_float2(lo, hi));
    return *reinterpret_cast<unsigned*>(&h2);
}

__device__ __forceinline__ unsigned wave_max_u32(unsigned v) {
    int x = (int)v, t;
    t = __builtin_amdgcn_update_dpp(x, x, 0x111, 0xF, 0xF, false); x = ((unsigned)t > (unsigned)x) ? t : x;
    t = __builtin_amdgcn_update_dpp(x, x, 0x112, 0xF, 0xF, false); x = ((unsigned)t > (unsigned)x) ? t : x;
    t = __builtin_amdgcn_update_dpp(x, x, 0x114, 0xF, 0xF, false); x = ((unsigned)t > (unsigned)x) ? t : x;
    t = __builtin_amdgcn_update_dpp(x, x, 0x118, 0xF, 0xF, false); x = ((unsigned)t > (unsigned)x) ? t : x;
    t = __builtin_amdgcn_update_dpp(x, x, 0x142, 0xa, 0xF, false); x = ((unsigned)t > (unsigned)x) ? t : x;
    t = __builtin_amdgcn_update_dpp(x, x, 0x143, 0xc, 0xF, false); x = ((unsigned)t > (unsigned)x) ? t : x;
    return (unsigned)__builtin_amdgcn_readlane(x, 63);
}

// ---- KNN: fp32 tournament prefilter (top-36) + fp64 exact re-rank --------
__global__ __launch_bounds__(512, 4) void knn_kernel(const float* __restrict__ x,
                                                     int* __restrict__ idxout) {
    __shared__ float4 ps[NPTS];   // (x, y, z, -|p|^2)  32 KB
    int t = threadIdx.x;
    int b = blockIdx.x / (NPTS / 8);
    int grp = blockIdx.x % (NPTS / 8);
    const float* xb = x + (size_t)b * 3 * NPTS;
    for (int i = t; i < NPTS; i += 512) {
        float vx = xb[i], vy = xb[NPTS + i], vz = xb[2 * NPTS + i];
        ps[i] = make_float4(vx, vy, vz, -((vx * vx + vy * vy) + vz * vz));
    }
    __syncthreads();
    int wave = t >> 6, lane = t & 63;
    int n = grp * 8 + wave;
    float4 pc = ps[n];
    float cx = pc.x, cy = pc.y, cz = pc.z;
    float sqn = pc.w;
    float cx2 = 2.0f * cx, cy2 = 2.0f * cy, cz2 = 2.0f * cz;

    unsigned key[32];
#pragma unroll
    for (int j = 0; j < 32; j++) {
        int cand = j * 64 + lane;
        float4 q = ps[cand];
        float v = sqn + q.w;
        v = fmaf(cx2, q.x, v);
        v = fmaf(cy2, q.y, v);
        v = fmaf(cz2, q.z, v);
        unsigned u = __float_as_uint(v);
        unsigned ord = u ^ ((u >> 31) ? 0xFFFFFFFFu : 0x80000000u);
        key[j] = (ord & 0xFFFFFFE0u) | (unsigned)j;
    }
#pragma unroll
    for (int k = 2; k <= 32; k <<= 1) {
#pragma unroll
        for (int j = k >> 1; j >= 1; j >>= 1) {
#pragma unroll
            for (int i = 0; i < 32; i++) {
                int l2 = i ^ j;
                if (l2 > i) {
                    unsigned a = key[i], bb = key[l2];
                    unsigned hi = a > bb ? a : bb, lo = a > bb ? bb : a;
                    if ((i & k) == 0) { key[i] = hi; key[l2] = lo; }
                    else              { key[i] = lo; key[l2] = hi; }
                }
            }
        }
    }
    // 36 tournament rounds (margin 4 over 32); per-lane survivor list cap 10
    int sg = 0;
    for (int r = 0; r < 36; r++) {
        unsigned m = wave_max_u32(key[0]);
        unsigned long long ball = __ballot(key[0] == m);
        int bl = __ffsll(ball) - 1;
        int gidx = (int)(m & 31u) * 64 + bl;
        if (lane == r) sg = gidx;
        bool won = (lane == bl);
#pragma unroll
        for (int i = 0; i < 9; i++) key[i] = won ? key[i + 1] : key[i];
        key[9] = won ? 0u : key[9];
    }
    double cxd = (double)cx, cyd = (double)cy, czd = (double)cz;
    double sqnd = -((cxd * cxd + cyd * cyd) + czd * czd);
    double v; int oid;
    if (lane < 36) {
        float4 qq = ps[sg];
        double mx = (double)qq.x, my = (double)qq.y, mz = (double)qq.z;
        double dot = (cxd * mx + cyd * my) + czd * mz;
        double sqm = -((mx * mx + my * my) + mz * mz);
        v = (sqnd + 2.0 * dot) + sqm;
        oid = sg;
    } else {
        v = -1.0e300; oid = (1 << 28) + lane;
    }
#pragma unroll
    for (int k = 2; k <= 64; k <<= 1) {
#pragma unroll
        for (int j = k >> 1; j >= 1; j >>= 1) {
            double ov = __shfl_xor(v, j);
            int oi = __shfl_xor(oid, j);
            bool amLow = (lane & j) == 0;
            bool asc = (lane & k) == 0;
            bool gt = (ov > v) || (ov == v && oi < oid);
            bool ga = gt != amLow;
            bool take = asc ? ga : !ga;
            if (take) { v = ov; oid = oi; }
        }
    }
    if (lane >= 32) idxout[((size_t)b * NPTS + n) * 32 + (63 - lane)] = oid;
}

// ---------------- feature transpose [B,64,N] -> bf16 [B,N,64] --------------
__global__ __launch_bounds__(256) void transpose_kernel(const float* __restrict__ feat,
                                                        unsigned short* __restrict__ fTb) {
    __shared__ float tile[64][65];
    int b = blockIdx.x / 32;
    int n0 = (blockIdx.x % 32) * 64;
    int t = threadIdx.x;
    int nt = t % 64, cg = t / 64;
    for (int cc = 0; cc < 16; cc++) {
        int c2 = cg * 16 + cc;
        tile[c2][nt] = feat[((size_t)b * 64 + c2) * NPTS + n0 + nt];
    }
    __syncthreads();
    int c2 = t % 64, ng = t / 64;
    for (int nn2 = 0; nn2 < 16; nn2++) {
        int n = ng * 16 + nn2;
        fTb[((size_t)b * NPTS + n0 + n) * 64 + c2] = f2bf(tile[c2][n]);
    }
}

// ---- weight prep: fold group-shuffle + MLP into WtT[oc][4096] bf16 --------
__global__ __launch_bounds__(256) void wprep2_kernel(
    const float* __restrict__ cw, const float* __restrict__ mlpw,
    const float* __restrict__ mb, const float* __restrict__ cb,
    unsigned short* __restrict__ WtT, float* __restrict__ cbw) {
    int oc = blockIdx.x;
    int t = threadIdx.x;
    for (int i = t; i < 2048; i += 256) {
        int f = i >> 5, col = i & 31;
        int r = (f % 24) * 4 + f / 24;
        WtT[(size_t)oc * KROW + i] = f2bf(cw[(size_t)oc * 3072 + r * 32 + col]);
    }
    for (int i = t; i < 2048; i += 256) {
        int j = i >> 5, col = i & 31;
        float s = 0.f;
        for (int o2 = 0; o2 < 32; o2++) {
            int f = 64 + o2;
            int r = (f % 24) * 4 + f / 24;
            s = fmaf(mlpw[o2 * 64 + j], cw[(size_t)oc * 3072 + r * 32 + col], s);
        }
        WtT[(size_t)oc * KROW + 2048 + i] = f2bf(s);
    }
    if (t == 0) {
        float s = cb[oc];
        for (int o2 = 0; o2 < 32; o2++) {
            int f = 64 + o2;
            int r = (f % 24) * 4 + f / 24;
            float rowsum = 0.f;
            for (int col = 0; col < 32; col++) rowsum += cw[(size_t)oc * 3072 + r * 32 + col];
            s = fmaf(mb[o2], rowsum, s);
        }
        cbw[oc] = s;
    }
}

__global__ void kprep_kernel(const float* __restrict__ ker, double* __restrict__ kerd) {
    int i = threadIdx.x;
    if (i < 96) kerd[i] = (double)ker[i];
}

// ---- perm kernel: 2 points/wave; fp64 p + top3 + softmax -> PTws bf16 ----
__global__ __launch_bounds__(256) void perm_kernel(
    const float* __restrict__ x, const int* __restrict__ idx,
    const double* __restrict__ kerd, unsigned short* __restrict__ PTws) {
    int t = threadIdx.x;
    int wv = t >> 6, l = t & 63;
    int c = l & 31;
    int cbase = l & 32;               // 0 for point A lanes, 32 for point B lanes
    int m = blockIdx.x * 8 + wv * 2 + (l >> 5);
    int b = m >> 11;
    int ik = idx[(size_t)m * 32 + c];
    const float* xb = x + (size_t)b * 3 * NPTS;
    float nx0 = xb[ik], ny0 = xb[NPTS + ik], nz0 = xb[2 * NPTS + ik];
    float cx = __shfl(nx0, cbase), cy = __shfl(ny0, cbase), cz = __shfl(nz0, cbase);
    double rxd = (double)nx0 - (double)cx;
    double ryd = (double)ny0 - (double)cy;
    double rzd = (double)nz0 - (double)cz;
    double ck0 = kerd[c], ck1 = kerd[32 + c], ck2 = kerd[64 + c];

    // p column c of own point: row kk's x_rel broadcast from lane cbase+kk
    double pd[32];
#pragma unroll
    for (int kk = 0; kk < 32; kk++) {
        double bx = __shfl(rxd, cbase + kk);
        double by = __shfl(ryd, cbase + kk);
        double bz = __shfl(rzd, cbase + kk);
        pd[kk] = bx * ck0 + by * ck1 + bz * ck2;
    }
    if (c == 0) pd[0] += 1.0;   // one_pad at (row 0, col 0), per point

    // branchless fp64 top-3
    double m1 = -1.0e300, m2 = -1.0e300, m3 = -1.0e300;
#pragma unroll
    for (int kk = 0; kk < 32; kk++) {
        double v = pd[kk];
        double t2 = fmin(v, m1);
        double t3 = fmin(v, m2);
        m1 = fmax(m1, v);
        m2 = fmax(m2, t2);
        m3 = fmax(m3, t3);
    }
    // fp64-exact threshold, fp32 softmax
    float pv[32];
    float ssum = 0.f;
#pragma unroll
    for (int kk = 0; kk < 32; kk++) {
        float e = (pd[kk] >= m3) ? __expf((float)(pd[kk] - m1)) : 0.f;
        pv[kk] = e; ssum += e;
    }
    float rs = 1.f / ssum;
#pragma unroll
    for (int kk = 0; kk < 32; kk++) pv[kk] *= rs;

    // pack row c (k-contiguous bf16) and store to PTws[m][c][0..31]
    unsigned w[16];
#pragma unroll
    for (int i = 0; i < 16; i++)
        w[i] = pk2bf(pv[2 * i], pv[2 * i + 1]);
    size_t obase = (size_t)m * 1024 + (size_t)c * 32;
    *(uint4*)&PTws[obase]      = make_uint4(w[0], w[1], w[2], w[3]);
    *(uint4*)&PTws[obase + 8]  = make_uint4(w[4], w[5], w[6], w[7]);
    *(uint4*)&PTws[obase + 16] = make_uint4(w[8], w[9], w[10], w[11]);
    *(uint4*)&PTws[obase + 24] = make_uint4(w[12], w[13], w[14], w[15]);
}

// ------- point3: gather + fourier + O=G*perm (MFMA); perm from PTws -------
__global__ __launch_bounds__(256) void point3_kernel(
    const float* __restrict__ x, const unsigned short* __restrict__ fTb,
    const int* __restrict__ idx, const float* __restrict__ Bm,
    const unsigned short* __restrict__ PTws, unsigned short* __restrict__ Aof,
    int m_base, int m_count) {
    __shared__ __align__(16) unsigned short lds2[4 * 2560];  // G2 only: 20480 B/block
    int t = threadIdx.x;
    int wv = t >> 6, l = t & 63;
    int k = l & 31, h = l >> 5;
    unsigned short* G2 = lds2 + wv * 2560;   // [64][40] bf16 (5120 B)
    int lr = l & 15, lq = l >> 4;
    int gw = blockIdx.x * 4 + wv;
    int nw = gridDim.x * 4;

    for (int mi = gw; mi < m_count; mi += nw) {
        int m = m_base + mi;
        int b = m >> 11;
        int ik = idx[(size_t)m * 32 + k];
        const float* xb = x + (size_t)b * 3 * NPTS;
        float nx0 = xb[ik], ny0 = xb[NPTS + ik], nz0 = xb[2 * NPTS + ik];
        // hoisted loads: features + perm fragments
        const unsigned short* fr = fTb + (((size_t)b * NPTS + ik) * 64 + h * 32);
        uint4 f0 = *(const uint4*)fr;
        uint4 f1 = *(const uint4*)(fr + 8);
        uint4 f2 = *(const uint4*)(fr + 16);
        uint4 f3 = *(const uint4*)(fr + 24);
        const unsigned short* ptp = PTws + (size_t)m * 1024;
        bf16x8 af0 = *(const bf16x8*)&ptp[lr * 32 + lq * 8];
        bf16x8 af1 = *(const bf16x8*)&ptp[(16 + lr) * 32 + lq * 8];

        float cx = __shfl(nx0, 0), cy = __shfl(ny0, 0), cz = __shfl(nz0, 0);
        float rx = nx0 - cx, ry = ny0 - cy, rz = nz0 - cz;
        float dist = sqrtf((rx * rx + ry * ry) + rz * rz);

        // G2 pass 1: gathered neighbor features rows 0..63, pair-pack across k
        {
            unsigned fw[16] = {f0.x, f0.y, f0.z, f0.w, f1.x, f1.y, f1.z, f1.w,
                               f2.x, f2.y, f2.z, f2.w, f3.x, f3.y, f3.z, f3.w};
#pragma unroll
            for (int c2 = 0; c2 < 16; c2++) {
                unsigned v = fw[c2];
                unsigned o = (unsigned)__shfl_xor((int)v, 1);
                unsigned wr = (k & 1) ? ((o >> 16) | (v & 0xFFFF0000u))
                                      : ((v & 0xFFFFu) | (o << 16));
                int ch = h * 32 + 2 * c2 + (k & 1);
                *(unsigned*)&G2[ch * 40 + (k & ~1)] = wr;
            }
        }
        asm volatile("" ::: "memory");

        // MFMA pass 1: O rows 0..63 (feats)
        size_t obase = (size_t)mi * KROW;
#pragma unroll
        for (int fb = 0; fb < 4; fb++) {
            int row = fb * 16 + lr;
            bf16x8 bfr = *(const bf16x8*)&G2[row * 40 + lq * 8];
            f32x4 d0 = __builtin_amdgcn_mfma_f32_16x16x32_bf16(af0, bfr, (f32x4){0.f, 0.f, 0.f, 0.f}, 0, 0, 0);
            f32x4 d1 = __builtin_amdgcn_mfma_f32_16x16x32_bf16(af1, bfr, (f32x4){0.f, 0.f, 0.f, 0.f}, 0, 0, 0);
            *(uint2*)&Aof[obase + row * 32 + lq * 4] =
                make_uint2(pk2bf(d0.x, d0.y), pk2bf(d0.z, d0.w));
            *(uint2*)&Aof[obase + row * 32 + 16 + lq * 4] =
                make_uint2(pk2bf(d1.x, d1.y), pk2bf(d1.z, d1.w));
        }
        asm volatile("" ::: "memory");

        // G2 pass 2: Fourier features rows 0..63 (sin 0..31, cos 32..63)
        // u computed as f32x2 pairs -> v_pk_fma_f32 / v_pk_mul_f32 (dual f32)
        {
            f32x2 u2[16];
#pragma unroll
            for (int i = 0; i < 16; i++) {
                f32x2 b0 = *(const f32x2*)&Bm[2 * i];
                f32x2 b1 = *(const f32x2*)&Bm[32 + 2 * i];
                f32x2 b2 = *(const f32x2*)&Bm[64 + 2 * i];
                f32x2 b3 = *(const f32x2*)&Bm[96 + 2 * i];
                f32x2 b4 = *(const f32x2*)&Bm[128 + 2 * i];
                f32x2 b5 = *(const f32x2*)&Bm[160 + 2 * i];
                f32x2 b6 = *(const f32x2*)&Bm[192 + 2 * i];
                f32x2 uu = cx * b0;
                uu = cy * b1 + uu;
                uu = cz * b2 + uu;
                uu = rx * b3 + uu;
                uu = ry * b4 + uu;
                uu = rz * b5 + uu;
                uu = dist * b6 + uu;
                u2[i] = 6.28318530717958647692f * uu;
            }
            float tv[32];
            if (h == 0) {
#pragma unroll
                for (int i = 0; i < 16; i++) {
                    tv[2 * i] = __sinf(u2[i][0]);
                    tv[2 * i + 1] = __sinf(u2[i][1]);
                }
            } else {
#pragma unroll
                for (int i = 0; i < 16; i++) {
                    tv[2 * i] = __cosf(u2[i][0]);
                    tv[2 * i + 1] = __cosf(u2[i][1]);
                }
            }
#pragma unroll
            for (int jj = 0; jj < 16; jj++) {
                float o0 = __shfl_xor(tv[jj], 1);
                float o1 = __shfl_xor(tv[jj + 16], 1);
                float lo = (k & 1) ? o1 : tv[jj];
                float hi = (k & 1) ? tv[jj + 16] : o0;
                unsigned wr = pk2bf(lo, hi);
                int row = h * 32 + (k & 1) * 16 + jj;
                *(unsigned*)&G2[row * 40 + (k & ~1)] = wr;
            }
        }
        asm volatile("" ::: "memory");

        // MFMA pass 2: O rows 64..127
#pragma unroll
        for (int fb = 0; fb < 4; fb++) {
            int row = fb * 16 + lr;
            bf16x8 bfr = *(const bf16x8*)&G2[row * 40 + lq * 8];
            f32x4 d0 = __builtin_amdgcn_mfma_f32_16x16x32_bf16(af0, bfr, (f32x4){0.f, 0.f, 0.f, 0.f}, 0, 0, 0);
            f32x4 d1 = __builtin_amdgcn_mfma_f32_16x16x32_bf16(af1, bfr, (f32x4){0.f, 0.f, 0.f, 0.f}, 0, 0, 0);
            int f = 64 + row;
            *(uint2*)&Aof[obase + f * 32 + lq * 4] =
                make_uint2(pk2bf(d0.x, d0.y), pk2bf(d0.z, d0.w));
            *(uint2*)&Aof[obase + f * 32 + 16 + lq * 4] =
                make_uint2(pk2bf(d1.x, d1.y), pk2bf(d1.z, d1.w));
        }
        asm volatile("" ::: "memory");
    }
}

// ---- conv3: 32-row tile, double-buffered LDS, fused BN partial sums ------
__global__ __launch_bounds__(256) void conv3_kernel(
    const unsigned short* __restrict__ A, const unsigned short* __restrict__ WtT,
    const float* __restrict__ cbw, float* __restrict__ outp,
    float* __restrict__ sums, int m_base) {
    __shared__ unsigned short Al[2][32 * 72];
    __shared__ unsigned short Wl[2][64 * 72];
    __shared__ float bnred[128];
    int t = threadIdx.x;
    int wv = t >> 6, l = t & 63;
    int lr = l & 15, lq = l >> 4;
    int m0 = blockIdx.x * 32;
    int ar = t >> 3, kq = t & 7;     // ar 0..31
    int mh = wv >> 1, oh = wv & 1;   // wave -> (m-half, oc-half)
    if (t < 128) bnred[t] = 0.f;
    f32x4 acc[2] = {};
    // prologue: stage ks=0 into buf 0
    {
        uint4 a0 = *(const uint4*)&A[(size_t)(m0 + ar) * KROW + kq * 8];
        uint4 w0 = *(const uint4*)&WtT[(size_t)ar * KROW + kq * 8];
        uint4 w1 = *(const uint4*)&WtT[(size_t)(ar + 32) * KROW + kq * 8];
        *(uint4*)&Al[0][ar * 72 + kq * 8] = a0;
        *(uint4*)&Wl[0][ar * 72 + kq * 8] = w0;
        *(uint4*)&Wl[0][(ar + 32) * 72 + kq * 8] = w1;
    }
    __syncthreads();
    int cur = 0;
    for (int ks = 0; ks < 64; ks++) {
        uint4 na0, nw0, nw1;
        bool pf = ks < 63;
        if (pf) {
            int k0 = (ks + 1) * 64;
            na0 = *(const uint4*)&A[(size_t)(m0 + ar) * KROW + k0 + kq * 8];
            nw0 = *(const uint4*)&WtT[(size_t)ar * KROW + k0 + kq * 8];
            nw1 = *(const uint4*)&WtT[(size_t)(ar + 32) * KROW + k0 + kq * 8];
        }
#pragma unroll
        for (int kk = 0; kk < 2; kk++) {
            bf16x8 af = *(const bf16x8*)&Al[cur][(mh * 16 + lr) * 72 + kk * 32 + lq * 8];
#pragma unroll
            for (int ocb = 0; ocb < 2; ocb++) {
                bf16x8 wf = *(const bf16x8*)&Wl[cur][(oh * 32 + ocb * 16 + lr) * 72 + kk * 32 + lq * 8];
                acc[ocb] = __builtin_amdgcn_mfma_f32_16x16x32_bf16(af, wf, acc[ocb], 0, 0, 0);
            }
        }
        if (pf) {
            *(uint4*)&Al[cur ^ 1][ar * 72 + kq * 8] = na0;
            *(uint4*)&Wl[cur ^ 1][ar * 72 + kq * 8] = nw0;
            *(uint4*)&Wl[cur ^ 1][(ar + 32) * 72 + kq * 8] = nw1;
            __syncthreads();
            cur ^= 1;
        }
    }
    // epilogue: store + BN partial sums
    int m = m_base + m0 + mh * 16 + lq * 4;
    int b = m >> 11, n = m & 2047;
#pragma unroll
    for (int ocb = 0; ocb < 2; ocb++) {
        int oc = oh * 32 + ocb * 16 + lr;
        float bias = cbw[oc];
        float4 v = make_float4(acc[ocb].x + bias, acc[ocb].y + bias,
                               acc[ocb].z + bias, acc[ocb].w + bias);
        *(float4*)&outp[((size_t)(b * 64 + oc)) * 2048 + n] = v;
        float s = (v.x + v.y) + (v.z + v.w);
        float s2 = fmaf(v.x, v.x, fmaf(v.y, v.y, fmaf(v.z, v.z, v.w * v.w)));
        atomicAdd(&bnred[oc * 2], s);
        atomicAdd(&bnred[oc * 2 + 1], s2);
    }
    __syncthreads();
    if (t < 64) {
        atomicAdd(&sums[t], bnred[t * 2]);
        atomicAdd(&sums[64 + t], bnred[t * 2 + 1]);
    }
}

__global__ __launch_bounds__(256) void bn2_kernel(float* __restrict__ outp,
                                                  const float* __restrict__ sums,
                                                  const float* __restrict__ gamma,
                                                  const float* __restrict__ beta) {
    int i = blockIdx.x * 256 + threadIdx.x;
    if (i >= MTOT * 64) return;
    int c = (i >> 11) & 63;
    float mean = sums[c] * (1.0f / (float)MTOT);
    float var = sums[64 + c] * (1.0f / (float)MTOT) - mean * mean;
    float inv = rsqrtf(var + 1e-5f);
    outp[i] = fmaf(gamma[c], (outp[i] - mean) * inv, beta[c]);
}

extern "C" void kernel_launch(void* const* d_in, const int* in_sizes, int n_in,
                              void* d_out, int out_size, void* d_ws, size_t ws_size,
                              hipStream_t stream) {
    (void)in_sizes; (void)n_in; (void)out_size;
    const float* x    = (const float*)d_in[0];
    const float* fea  = (const float*)d_in[1];
    const float* Bm   = (const float*)d_in[2];
    const float* ker  = (const float*)d_in[3];
    const float* mw   = (const float*)d_in[4];
    const float* mb   = (const float*)d_in[5];
    const float* cw   = (const float*)d_in[6];
    const float* cb   = (const float*)d_in[7];
    const float* gam  = (const float*)d_in[8];
    const float* bet  = (const float*)d_in[9];
    float* outp = (float*)d_out;

    char* wsb = (char*)d_ws;
    size_t off = 0;
    auto carve = [&](size_t sz) {
        void* p = wsb + off;
        off = (off + sz + 255) & ~(size_t)255;
        return p;
    };
    unsigned short* fTb  = (unsigned short*)carve((size_t)MTOT * 64 * 2);
    int*            idxw = (int*)carve((size_t)MTOT * 32 * 4);
    unsigned short* WtT  = (unsigned short*)carve((size_t)OUTC * KROW * 2);
    float*          cbw  = (float*)carve(64 * 4);
    double*         kerd = (double*)carve(96 * 8);
    float*          sums = (float*)carve(2 * 64 * 4);
    unsigned short* PTws = (unsigned short*)carve((size_t)MTOT * 1024 * 2);  // 32 MB
    size_t fixedEnd = off;
    int CS = 16384;
    while (fixedEnd + (size_t)CS * KROW * 2 > ws_size && CS > 2048) CS >>= 1;
    unsigned short* Aof = (unsigned short*)(wsb + fixedEnd);

    hipMemsetAsync(sums, 0, 2 * 64 * 4, stream);
    knn_kernel<<<NBATCH * (NPTS / 8), 512, 0, stream>>>(x, idxw);
    transpose_kernel<<<NBATCH * 32, 256, 0, stream>>>(fea, fTb);
    wprep2_kernel<<<64, 256, 0, stream>>>(cw, mw, mb, cb, WtT, cbw);
    kprep_kernel<<<1, 128, 0, stream>>>(ker, kerd);
    perm_kernel<<<MTOT / 8, 256, 0, stream>>>(x, idxw, kerd, PTws);

    for (int c0 = 0; c0 < MTOT; c0 += CS) {
        point3_kernel<<<2048, 256, 0, stream>>>(x, fTb, idxw, Bm, PTws, Aof, c0, CS);
        conv3_kernel<<<CS / 32, 256, 0, stream>>>(Aof, WtT, cbw, outp, sums, c0);
    }
    bn2_kernel<<<(MTOT * 64 + 255) / 256, 256, 0, stream>>>(outp, sums, gam, bet);
}

// Round 16
// 183.141 us; speedup vs baseline: 1.0154x; 1.0154x over previous
//
#include <hip/hip_runtime.h>
#include <hip/hip_bf16.h>
#include <math.h>

#define NPTS 2048
#define NBATCH 8
#define MTOT (NBATCH*NPTS)
#define KROW 4096   // conv K: 128 rows * 32 cols
#define OUTC 64

using bf16x8 = __attribute__((ext_vector_type(8))) short;
using f32x4  = __attribute__((ext_vector_type(4))) float;

__device__ __forceinline__ unsigned short f2bf(float f) {
    unsigned u = __float_as_uint(f);
    unsigned r = u + 0x7FFFu + ((u >> 16) & 1u);
    return (unsigned short)(r >> 16);
}
// pair-pack via compiler-fused v_cvt_pk_bf16_f32 (RNE, identical to f2bf)
__device__ __forceinline__ unsigned pk2bf(float lo, float hi) {
    __hip_bfloat162 h2 = __float22bfloat162_rn(make_float2(lo, hi));
    return *reinterpret_cast<unsigned*>(&h2);
}

__device__ __forceinline__ unsigned wave_max_u32(unsigned v) {
    int x = (int)v, t;
    t = __builtin_amdgcn_update_dpp(x, x, 0x111, 0xF, 0xF, false); x = ((unsigned)t > (unsigned)x) ? t : x;
    t = __builtin_amdgcn_update_dpp(x, x, 0x112, 0xF, 0xF, false); x = ((unsigned)t > (unsigned)x) ? t : x;
    t = __builtin_amdgcn_update_dpp(x, x, 0x114, 0xF, 0xF, false); x = ((unsigned)t > (unsigned)x) ? t : x;
    t = __builtin_amdgcn_update_dpp(x, x, 0x118, 0xF, 0xF, false); x = ((unsigned)t > (unsigned)x) ? t : x;
    t = __builtin_amdgcn_update_dpp(x, x, 0x142, 0xa, 0xF, false); x = ((unsigned)t > (unsigned)x) ? t : x;
    t = __builtin_amdgcn_update_dpp(x, x, 0x143, 0xc, 0xF, false); x = ((unsigned)t > (unsigned)x) ? t : x;
    return (unsigned)__builtin_amdgcn_readlane(x, 63);
}

// ---- KNN: fp32 tournament prefilter (top-36) + fp64 exact re-rank --------
__global__ __launch_bounds__(512, 4) void knn_kernel(const float* __restrict__ x,
                                                     int* __restrict__ idxout) {
    __shared__ float4 ps[NPTS];   // (x, y, z, -|p|^2)  32 KB
    int t = threadIdx.x;
    int b = blockIdx.x / (NPTS / 8);
    int grp = blockIdx.x % (NPTS / 8);
    const float* xb = x + (size_t)b * 3 * NPTS;
    for (int i = t; i < NPTS; i += 512) {
        float vx = xb[i], vy = xb[NPTS + i], vz = xb[2 * NPTS + i];
        ps[i] = make_float4(vx, vy, vz, -((vx * vx + vy * vy) + vz * vz));
    }
    __syncthreads();
    int wave = t >> 6, lane = t & 63;
    int n = grp * 8 + wave;
    float4 pc = ps[n];
    float cx = pc.x, cy = pc.y, cz = pc.z;
    float sqn = pc.w;
    float cx2 = 2.0f * cx, cy2 = 2.0f * cy, cz2 = 2.0f * cz;

    unsigned key[32];
#pragma unroll
    for (int j = 0; j < 32; j++) {
        int cand = j * 64 + lane;
        float4 q = ps[cand];
        float v = sqn + q.w;
        v = fmaf(cx2, q.x, v);
        v = fmaf(cy2, q.y, v);
        v = fmaf(cz2, q.z, v);
        unsigned u = __float_as_uint(v);
        unsigned ord = u ^ ((u >> 31) ? 0xFFFFFFFFu : 0x80000000u);
        key[j] = (ord & 0xFFFFFFE0u) | (unsigned)j;
    }
#pragma unroll
    for (int k = 2; k <= 32; k <<= 1) {
#pragma unroll
        for (int j = k >> 1; j >= 1; j >>= 1) {
#pragma unroll
            for (int i = 0; i < 32; i++) {
                int l2 = i ^ j;
                if (l2 > i) {
                    unsigned a = key[i], bb = key[l2];
                    unsigned hi = a > bb ? a : bb, lo = a > bb ? bb : a;
                    if ((i & k) == 0) { key[i] = hi; key[l2] = lo; }
                    else              { key[i] = lo; key[l2] = hi; }
                }
            }
        }
    }
    // 36 tournament rounds (margin 4 over 32); per-lane survivor list cap 10
    int sg = 0;
    for (int r = 0; r < 36; r++) {
        unsigned m = wave_max_u32(key[0]);
        unsigned long long ball = __ballot(key[0] == m);
        int bl = __ffsll(ball) - 1;
        int gidx = (int)(m & 31u) * 64 + bl;
        if (lane == r) sg = gidx;
        bool won = (lane == bl);
#pragma unroll
        for (int i = 0; i < 9; i++) key[i] = won ? key[i + 1] : key[i];
        key[9] = won ? 0u : key[9];
    }
    double cxd = (double)cx, cyd = (double)cy, czd = (double)cz;
    double sqnd = -((cxd * cxd + cyd * cyd) + czd * czd);
    double v; int oid;
    if (lane < 36) {
        float4 qq = ps[sg];
        double mx = (double)qq.x, my = (double)qq.y, mz = (double)qq.z;
        double dot = (cxd * mx + cyd * my) + czd * mz;
        double sqm = -((mx * mx + my * my) + mz * mz);
        v = (sqnd + 2.0 * dot) + sqm;
        oid = sg;
    } else {
        v = -1.0e300; oid = (1 << 28) + lane;
    }
#pragma unroll
    for (int k = 2; k <= 64; k <<= 1) {
#pragma unroll
        for (int j = k >> 1; j >= 1; j >>= 1) {
            double ov = __shfl_xor(v, j);
            int oi = __shfl_xor(oid, j);
            bool amLow = (lane & j) == 0;
            bool asc = (lane & k) == 0;
            bool gt = (ov > v) || (ov == v && oi < oid);
            bool ga = gt != amLow;
            bool take = asc ? ga : !ga;
            if (take) { v = ov; oid = oi; }
        }
    }
    if (lane >= 32) idxout[((size_t)b * NPTS + n) * 32 + (63 - lane)] = oid;
}

// ---------------- feature transpose [B,64,N] -> bf16 [B,N,64] --------------
__global__ __launch_bounds__(256) void transpose_kernel(const float* __restrict__ feat,
                                                        unsigned short* __restrict__ fTb) {
    __shared__ float tile[64][65];
    int b = blockIdx.x / 32;
    int n0 = (blockIdx.x % 32) * 64;
    int t = threadIdx.x;
    int nt = t % 64, cg = t / 64;
    for (int cc = 0; cc < 16; cc++) {
        int c2 = cg * 16 + cc;
        tile[c2][nt] = feat[((size_t)b * 64 + c2) * NPTS + n0 + nt];
    }
    __syncthreads();
    int c2 = t % 64, ng = t / 64;
    for (int nn2 = 0; nn2 < 16; nn2++) {
        int n = ng * 16 + nn2;
        fTb[((size_t)b * NPTS + n0 + n) * 64 + c2] = f2bf(tile[c2][n]);
    }
}

// ---- weight prep: fold group-shuffle + MLP into WtT[oc][4096] bf16;
//      block 0 also widens kernels to fp64 (old kprep) ---------------------
__global__ __launch_bounds__(256) void wprep2_kernel(
    const float* __restrict__ cw, const float* __restrict__ mlpw,
    const float* __restrict__ mb, const float* __restrict__ cb,
    const float* __restrict__ ker, double* __restrict__ kerd,
    unsigned short* __restrict__ WtT, float* __restrict__ cbw) {
    int oc = blockIdx.x;
    int t = threadIdx.x;
    if (oc == 0 && t < 96) kerd[t] = (double)ker[t];
    for (int i = t; i < 2048; i += 256) {
        int f = i >> 5, col = i & 31;
        int r = (f % 24) * 4 + f / 24;
        WtT[(size_t)oc * KROW + i] = f2bf(cw[(size_t)oc * 3072 + r * 32 + col]);
    }
    for (int i = t; i < 2048; i += 256) {
        int j = i >> 5, col = i & 31;
        float s = 0.f;
        for (int o2 = 0; o2 < 32; o2++) {
            int f = 64 + o2;
            int r = (f % 24) * 4 + f / 24;
            s = fmaf(mlpw[o2 * 64 + j], cw[(size_t)oc * 3072 + r * 32 + col], s);
        }
        WtT[(size_t)oc * KROW + 2048 + i] = f2bf(s);
    }
    if (t == 0) {
        float s = cb[oc];
        for (int o2 = 0; o2 < 32; o2++) {
            int f = 64 + o2;
            int r = (f % 24) * 4 + f / 24;
            float rowsum = 0.f;
            for (int col = 0; col < 32; col++) rowsum += cw[(size_t)oc * 3072 + r * 32 + col];
            s = fmaf(mb[o2], rowsum, s);
        }
        cbw[oc] = s;
    }
}

// ---- perm kernel: 2 points/wave; fp64 p + top3 + softmax -> PTws bf16 ----
__global__ __launch_bounds__(256) void perm_kernel(
    const float* __restrict__ x, const int* __restrict__ idx,
    const double* __restrict__ kerd, unsigned short* __restrict__ PTws) {
    int t = threadIdx.x;
    int wv = t >> 6, l = t & 63;
    int c = l & 31;
    int cbase = l & 32;               // 0 for point A lanes, 32 for point B lanes
    int m = blockIdx.x * 8 + wv * 2 + (l >> 5);
    int b = m >> 11;
    int ik = idx[(size_t)m * 32 + c];
    const float* xb = x + (size_t)b * 3 * NPTS;
    float nx0 = xb[ik], ny0 = xb[NPTS + ik], nz0 = xb[2 * NPTS + ik];
    float cx = __shfl(nx0, cbase), cy = __shfl(ny0, cbase), cz = __shfl(nz0, cbase);
    double rxd = (double)nx0 - (double)cx;
    double ryd = (double)ny0 - (double)cy;
    double rzd = (double)nz0 - (double)cz;
    double ck0 = kerd[c], ck1 = kerd[32 + c], ck2 = kerd[64 + c];

    // p column c of own point: row kk's x_rel broadcast from lane cbase+kk
    double pd[32];
#pragma unroll
    for (int kk = 0; kk < 32; kk++) {
        double bx = __shfl(rxd, cbase + kk);
        double by = __shfl(ryd, cbase + kk);
        double bz = __shfl(rzd, cbase + kk);
        pd[kk] = bx * ck0 + by * ck1 + bz * ck2;
    }
    if (c == 0) pd[0] += 1.0;   // one_pad at (row 0, col 0), per point

    // branchless fp64 top-3
    double m1 = -1.0e300, m2 = -1.0e300, m3 = -1.0e300;
#pragma unroll
    for (int kk = 0; kk < 32; kk++) {
        double v = pd[kk];
        double t2 = fmin(v, m1);
        double t3 = fmin(v, m2);
        m1 = fmax(m1, v);
        m2 = fmax(m2, t2);
        m3 = fmax(m3, t3);
    }
    // fp64-exact threshold, fp32 softmax
    float pv[32];
    float ssum = 0.f;
#pragma unroll
    for (int kk = 0; kk < 32; kk++) {
        float e = (pd[kk] >= m3) ? __expf((float)(pd[kk] - m1)) : 0.f;
        pv[kk] = e; ssum += e;
    }
    float rs = 1.f / ssum;
#pragma unroll
    for (int kk = 0; kk < 32; kk++) pv[kk] *= rs;

    // pack row c (k-contiguous bf16) and store to PTws[m][c][0..31]
    unsigned w[16];
#pragma unroll
    for (int i = 0; i < 16; i++)
        w[i] = pk2bf(pv[2 * i], pv[2 * i + 1]);
    size_t obase = (size_t)m * 1024 + (size_t)c * 32;
    *(uint4*)&PTws[obase]      = make_uint4(w[0], w[1], w[2], w[3]);
    *(uint4*)&PTws[obase + 8]  = make_uint4(w[4], w[5], w[6], w[7]);
    *(uint4*)&PTws[obase + 16] = make_uint4(w[8], w[9], w[10], w[11]);
    *(uint4*)&PTws[obase + 24] = make_uint4(w[12], w[13], w[14], w[15]);
}

// ------- point3: gather + fourier + O=G*perm (MFMA); perm from PTws -------
__global__ __launch_bounds__(256) void point3_kernel(
    const float* __restrict__ x, const unsigned short* __restrict__ fTb,
    const int* __restrict__ idx, const float* __restrict__ Bm,
    const unsigned short* __restrict__ PTws, unsigned short* __restrict__ Aof,
    int m_base, int m_count) {
    __shared__ __align__(16) unsigned short lds2[4 * 2560];  // G2 only: 20480 B/block
    int t = threadIdx.x;
    int wv = t >> 6, l = t & 63;
    int k = l & 31, h = l >> 5;
    unsigned short* G2 = lds2 + wv * 2560;   // [64][40] bf16 (5120 B)
    int lr = l & 15, lq = l >> 4;
    int gw = blockIdx.x * 4 + wv;
    int nw = gridDim.x * 4;

    for (int mi = gw; mi < m_count; mi += nw) {
        int m = m_base + mi;
        int b = m >> 11;
        int ik = idx[(size_t)m * 32 + k];
        const float* xb = x + (size_t)b * 3 * NPTS;
        float nx0 = xb[ik], ny0 = xb[NPTS + ik], nz0 = xb[2 * NPTS + ik];
        // hoisted loads: features + perm fragments
        const unsigned short* fr = fTb + (((size_t)b * NPTS + ik) * 64 + h * 32);
        uint4 f0 = *(const uint4*)fr;
        uint4 f1 = *(const uint4*)(fr + 8);
        uint4 f2 = *(const uint4*)(fr + 16);
        uint4 f3 = *(const uint4*)(fr + 24);
        const unsigned short* ptp = PTws + (size_t)m * 1024;
        bf16x8 af0 = *(const bf16x8*)&ptp[lr * 32 + lq * 8];
        bf16x8 af1 = *(const bf16x8*)&ptp[(16 + lr) * 32 + lq * 8];

        float cx = __shfl(nx0, 0), cy = __shfl(ny0, 0), cz = __shfl(nz0, 0);
        float rx = nx0 - cx, ry = ny0 - cy, rz = nz0 - cz;
        float dist = sqrtf((rx * rx + ry * ry) + rz * rz);

        // G2 pass 1: gathered neighbor features rows 0..63, pair-pack across k
        {
            unsigned fw[16] = {f0.x, f0.y, f0.z, f0.w, f1.x, f1.y, f1.z, f1.w,
                               f2.x, f2.y, f2.z, f2.w, f3.x, f3.y, f3.z, f3.w};
#pragma unroll
            for (int c2 = 0; c2 < 16; c2++) {
                unsigned v = fw[c2];
                unsigned o = (unsigned)__shfl_xor((int)v, 1);
                unsigned wr = (k & 1) ? ((o >> 16) | (v & 0xFFFF0000u))
                                      : ((v & 0xFFFFu) | (o << 16));
                int ch = h * 32 + 2 * c2 + (k & 1);
                *(unsigned*)&G2[ch * 40 + (k & ~1)] = wr;
            }
        }
        asm volatile("" ::: "memory");

        // MFMA pass 1: O rows 0..63 (feats)
        size_t obase = (size_t)mi * KROW;
#pragma unroll
        for (int fb = 0; fb < 4; fb++) {
            int row = fb * 16 + lr;
            bf16x8 bfr = *(const bf16x8*)&G2[row * 40 + lq * 8];
            f32x4 d0 = __builtin_amdgcn_mfma_f32_16x16x32_bf16(af0, bfr, (f32x4){0.f, 0.f, 0.f, 0.f}, 0, 0, 0);
            f32x4 d1 = __builtin_amdgcn_mfma_f32_16x16x32_bf16(af1, bfr, (f32x4){0.f, 0.f, 0.f, 0.f}, 0, 0, 0);
            *(uint2*)&Aof[obase + row * 32 + lq * 4] =
                make_uint2(pk2bf(d0.x, d0.y), pk2bf(d0.z, d0.w));
            *(uint2*)&Aof[obase + row * 32 + 16 + lq * 4] =
                make_uint2(pk2bf(d1.x, d1.y), pk2bf(d1.z, d1.w));
        }
        asm volatile("" ::: "memory");

        // G2 pass 2: Fourier features rows 0..63 (sin 0..31, cos 32..63)
        {
            float u[32];
#pragma unroll
            for (int f = 0; f < 32; f++) {
                float uu = cx * Bm[f];
                uu = fmaf(cy, Bm[32 + f], uu);
                uu = fmaf(cz, Bm[64 + f], uu);
                uu = fmaf(rx, Bm[96 + f], uu);
                uu = fmaf(ry, Bm[128 + f], uu);
                uu = fmaf(rz, Bm[160 + f], uu);
                uu = fmaf(dist, Bm[192 + f], uu);
                u[f] = 6.28318530717958647692f * uu;
            }
            float tv[32];
            if (h == 0) {
#pragma unroll
                for (int f = 0; f < 32; f++) tv[f] = __sinf(u[f]);
            } else {
#pragma unroll
                for (int f = 0; f < 32; f++) tv[f] = __cosf(u[f]);
            }
#pragma unroll
            for (int jj = 0; jj < 16; jj++) {
                float o0 = __shfl_xor(tv[jj], 1);
                float o1 = __shfl_xor(tv[jj + 16], 1);
                float lo = (k & 1) ? o1 : tv[jj];
                float hi = (k & 1) ? tv[jj + 16] : o0;
                unsigned wr = pk2bf(lo, hi);
                int row = h * 32 + (k & 1) * 16 + jj;
                *(unsigned*)&G2[row * 40 + (k & ~1)] = wr;
            }
        }
        asm volatile("" ::: "memory");

        // MFMA pass 2: O rows 64..127
#pragma unroll
        for (int fb = 0; fb < 4; fb++) {
            int row = fb * 16 + lr;
            bf16x8 bfr = *(const bf16x8*)&G2[row * 40 + lq * 8];
            f32x4 d0 = __builtin_amdgcn_mfma_f32_16x16x32_bf16(af0, bfr, (f32x4){0.f, 0.f, 0.f, 0.f}, 0, 0, 0);
            f32x4 d1 = __builtin_amdgcn_mfma_f32_16x16x32_bf16(af1, bfr, (f32x4){0.f, 0.f, 0.f, 0.f}, 0, 0, 0);
            int f = 64 + row;
            *(uint2*)&Aof[obase + f * 32 + lq * 4] =
                make_uint2(pk2bf(d0.x, d0.y), pk2bf(d0.z, d0.w));
            *(uint2*)&Aof[obase + f * 32 + 16 + lq * 4] =
                make_uint2(pk2bf(d1.x, d1.y), pk2bf(d1.z, d1.w));
        }
        asm volatile("" ::: "memory");
    }
}

// ---- conv3: 32-row tile, double-buffered LDS, fused BN partial sums ------
__global__ __launch_bounds__(256) void conv3_kernel(
    const unsigned short* __restrict__ A, const unsigned short* __restrict__ WtT,
    const float* __restrict__ cbw, float* __restrict__ outp,
    float* __restrict__ sums, int m_base) {
    __shared__ unsigned short Al[2][32 * 72];
    __shared__ unsigned short Wl[2][64 * 72];
    __shared__ float bnred[128];
    int t = threadIdx.x;
    int wv = t >> 6, l = t & 63;
    int lr = l & 15, lq = l >> 4;
    int m0 = blockIdx.x * 32;
    int ar = t >> 3, kq = t & 7;     // ar 0..31
    int mh = wv >> 1, oh = wv & 1;   // wave -> (m-half, oc-half)
    if (t < 128) bnred[t] = 0.f;
    f32x4 acc[2] = {};
    // prologue: stage ks=0 into buf 0
    {
        uint4 a0 = *(const uint4*)&A[(size_t)(m0 + ar) * KROW + kq * 8];
        uint4 w0 = *(const uint4*)&WtT[(size_t)ar * KROW + kq * 8];
        uint4 w1 = *(const uint4*)&WtT[(size_t)(ar + 32) * KROW + kq * 8];
        *(uint4*)&Al[0][ar * 72 + kq * 8] = a0;
        *(uint4*)&Wl[0][ar * 72 + kq * 8] = w0;
        *(uint4*)&Wl[0][(ar + 32) * 72 + kq * 8] = w1;
    }
    __syncthreads();
    int cur = 0;
    for (int ks = 0; ks < 64; ks++) {
        uint4 na0, nw0, nw1;
        bool pf = ks < 63;
        if (pf) {
            int k0 = (ks + 1) * 64;
            na0 = *(const uint4*)&A[(size_t)(m0 + ar) * KROW + k0 + kq * 8];
            nw0 = *(const uint4*)&WtT[(size_t)ar * KROW + k0 + kq * 8];
            nw1 = *(const uint4*)&WtT[(size_t)(ar + 32) * KROW + k0 + kq * 8];
        }
#pragma unroll
        for (int kk = 0; kk < 2; kk++) {
            bf16x8 af = *(const bf16x8*)&Al[cur][(mh * 16 + lr) * 72 + kk * 32 + lq * 8];
#pragma unroll
            for (int ocb = 0; ocb < 2; ocb++) {
                bf16x8 wf = *(const bf16x8*)&Wl[cur][(oh * 32 + ocb * 16 + lr) * 72 + kk * 32 + lq * 8];
                acc[ocb] = __builtin_amdgcn_mfma_f32_16x16x32_bf16(af, wf, acc[ocb], 0, 0, 0);
            }
        }
        if (pf) {
            *(uint4*)&Al[cur ^ 1][ar * 72 + kq * 8] = na0;
            *(uint4*)&Wl[cur ^ 1][ar * 72 + kq * 8] = nw0;
            *(uint4*)&Wl[cur ^ 1][(ar + 32) * 72 + kq * 8] = nw1;
            __syncthreads();
            cur ^= 1;
        }
    }
    // epilogue: store + BN partial sums
    int m = m_base + m0 + mh * 16 + lq * 4;
    int b = m >> 11, n = m & 2047;
#pragma unroll
    for (int ocb = 0; ocb < 2; ocb++) {
        int oc = oh * 32 + ocb * 16 + lr;
        float bias = cbw[oc];
        float4 v = make_float4(acc[ocb].x + bias, acc[ocb].y + bias,
                               acc[ocb].z + bias, acc[ocb].w + bias);
        *(float4*)&outp[((size_t)(b * 64 + oc)) * 2048 + n] = v;
        float s = (v.x + v.y) + (v.z + v.w);
        float s2 = fmaf(v.x, v.x, fmaf(v.y, v.y, fmaf(v.z, v.z, v.w * v.w)));
        atomicAdd(&bnred[oc * 2], s);
        atomicAdd(&bnred[oc * 2 + 1], s2);
    }
    __syncthreads();
    if (t < 64) {
        atomicAdd(&sums[t], bnred[t * 2]);
        atomicAdd(&sums[64 + t], bnred[t * 2 + 1]);
    }
}

__global__ __launch_bounds__(256) void bn2_kernel(float* __restrict__ outp,
                                                  const float* __restrict__ sums,
                                                  const float* __restrict__ gamma,
                                                  const float* __restrict__ beta) {
    int i = blockIdx.x * 256 + threadIdx.x;
    if (i >= MTOT * 64) return;
    int c = (i >> 11) & 63;
    float mean = sums[c] * (1.0f / (float)MTOT);
    float var = sums[64 + c] * (1.0f / (float)MTOT) - mean * mean;
    float inv = rsqrtf(var + 1e-5f);
    outp[i] = fmaf(gamma[c], (outp[i] - mean) * inv, beta[c]);
}

extern "C" void kernel_launch(void* const* d_in, const int* in_sizes, int n_in,
                              void* d_out, int out_size, void* d_ws, size_t ws_size,
                              hipStream_t stream) {
    (void)in_sizes; (void)n_in; (void)out_size;
    const float* x    = (const float*)d_in[0];
    const float* fea  = (const float*)d_in[1];
    const float* Bm   = (const float*)d_in[2];
    const float* ker  = (const float*)d_in[3];
    const float* mw   = (const float*)d_in[4];
    const float* mb   = (const float*)d_in[5];
    const float* cw   = (const float*)d_in[6];
    const float* cb   = (const float*)d_in[7];
    const float* gam  = (const float*)d_in[8];
    const float* bet  = (const float*)d_in[9];
    float* outp = (float*)d_out;

    char* wsb = (char*)d_ws;
    size_t off = 0;
    auto carve = [&](size_t sz) {
        void* p = wsb + off;
        off = (off + sz + 255) & ~(size_t)255;
        return p;
    };
    unsigned short* fTb  = (unsigned short*)carve((size_t)MTOT * 64 * 2);
    int*            idxw = (int*)carve((size_t)MTOT * 32 * 4);
    unsigned short* WtT  = (unsigned short*)carve((size_t)OUTC * KROW * 2);
    float*          cbw  = (float*)carve(64 * 4);
    double*         kerd = (double*)carve(96 * 8);
    float*          sums = (float*)carve(2 * 64 * 4);
    unsigned short* PTws = (unsigned short*)carve((size_t)MTOT * 1024 * 2);  // 32 MB
    size_t fixedEnd = off;
    int CS = 16384;
    while (fixedEnd + (size_t)CS * KROW * 2 > ws_size && CS > 2048) CS >>= 1;
    unsigned short* Aof = (unsigned short*)(wsb + fixedEnd);

    hipMemsetAsync(sums, 0, 2 * 64 * 4, stream);
    knn_kernel<<<NBATCH * (NPTS / 8), 512, 0, stream>>>(x, idxw);
    transpose_kernel<<<NBATCH * 32, 256, 0, stream>>>(fea, fTb);
    wprep2_kernel<<<64, 256, 0, stream>>>(cw, mw, mb, cb, ker, kerd, WtT, cbw);
    perm_kernel<<<MTOT / 8, 256, 0, stream>>>(x, idxw, kerd, PTws);

    for (int c0 = 0; c0 < MTOT; c0 += CS) {
        point3_kernel<<<2048, 256, 0, stream>>>(x, fTb, idxw, Bm, PTws, Aof, c0, CS);
        conv3_kernel<<<CS / 32, 256, 0, stream>>>(Aof, WtT, cbw, outp, sums, c0);
    }
    bn2_kernel<<<(MTOT * 64 + 255) / 256, 256, 0, stream>>>(outp, sums, gam, bet);
}